// Round 1
// baseline (585.638 us; speedup 1.0000x reference)
//
#include <hip/hip_runtime.h>

#define BB 32
#define CC 3072
#define HWD 784     // 28*28
#define L1 9
#define NCLS 200
#define CSPLIT 8
#define CCHUNK 384  // CC / CSPLIT

// d_out layout (floats):
//   all_features (B,C,L1)   @ 0         count 884736
//   maps         (B,L1,H,W) @ 884736    count 225792
//   scores       (B,200,8)  @ 1110528   count 51200
//   dist         (B,L1,H,W) @ 1161728   count 225792
#define AF_OFF     0
#define MAPS_OFF   884736
#define SCORES_OFF 1110528
#define DIST_OFF   1161728

// ---------------- Kernel A: partial ab[9] + bsq per (pixel, c-chunk) ----------------
// grid (128, 8): blockIdx.x = b*4+pb, blockIdx.y = cs. block 256.
// partial layout: [b][pix][cs][10]  (10 = 9 ab + 1 bsq)
__global__ __launch_bounds__(256) void kA(const float* __restrict__ feat,
                                          const float* __restrict__ w_land,
                                          float* __restrict__ partial) {
    __shared__ __align__(16) float ws[L1 * CCHUNK];
    const int tid = threadIdx.x;
    const int b = blockIdx.x >> 2, pb = blockIdx.x & 3;
    const int cs = blockIdx.y;
    for (int i = tid; i < L1 * CCHUNK; i += 256) {
        int l = i / CCHUNK, cc = i - l * CCHUNK;
        ws[i] = w_land[l * CC + cs * CCHUNK + cc];
    }
    __syncthreads();
    const int pix = pb * 256 + tid;
    if (pix >= HWD) return;

    float ab[L1];
    #pragma unroll
    for (int l = 0; l < L1; ++l) ab[l] = 0.f;
    float bsq = 0.f;

    const float* fp = feat + ((size_t)b * CC + (size_t)cs * CCHUNK) * HWD + pix;
    for (int cc = 0; cc < CCHUNK; cc += 4) {
        float v0 = fp[(size_t)(cc + 0) * HWD];
        float v1 = fp[(size_t)(cc + 1) * HWD];
        float v2 = fp[(size_t)(cc + 2) * HWD];
        float v3 = fp[(size_t)(cc + 3) * HWD];
        bsq += v0 * v0 + v1 * v1 + v2 * v2 + v3 * v3;
        #pragma unroll
        for (int l = 0; l < L1; ++l) {
            const float4 w4 = *(const float4*)&ws[l * CCHUNK + cc];
            ab[l] += v0 * w4.x + v1 * w4.y + v2 * w4.z + v3 * w4.w;
        }
    }
    float* out = partial + (((size_t)b * HWD + pix) * CSPLIT + cs) * 10;
    #pragma unroll
    for (int l = 0; l < L1; ++l) out[l] = ab[l];
    out[L1] = bsq;
}

// ---------------- Kernel B: reduce partials, softmax -> maps, dist ----------------
// grid 128: blockIdx.x = b*4+pb. block 256, thread = pixel.
__global__ __launch_bounds__(256) void kB(const float* __restrict__ w_land,
                                          const float* __restrict__ partial,
                                          float* __restrict__ maps_out,
                                          float* __restrict__ dist_out) {
    __shared__ float asq_s[4][L1];
    const int tid = threadIdx.x;
    const int lane = tid & 63, wv = tid >> 6;

    // a_sq[l] = sum_c w[l][c]^2, computed cooperatively (w_land is L2-hot)
    float s[L1];
    #pragma unroll
    for (int l = 0; l < L1; ++l) s[l] = 0.f;
    for (int c = tid; c < CC; c += 256) {
        #pragma unroll
        for (int l = 0; l < L1; ++l) {
            float w = w_land[l * CC + c];
            s[l] += w * w;
        }
    }
    #pragma unroll
    for (int l = 0; l < L1; ++l) {
        float v = s[l];
        for (int off = 32; off; off >>= 1) v += __shfl_xor(v, off);
        s[l] = v;
    }
    if (lane == 0) {
        #pragma unroll
        for (int l = 0; l < L1; ++l) asq_s[wv][l] = s[l];
    }
    __syncthreads();

    const int b = blockIdx.x >> 2, pb = blockIdx.x & 3;
    const int pix = pb * 256 + tid;
    if (pix >= HWD) return;

    float asq[L1];
    #pragma unroll
    for (int l = 0; l < L1; ++l)
        asq[l] = asq_s[0][l] + asq_s[1][l] + asq_s[2][l] + asq_s[3][l];

    const float* pp = partial + ((size_t)b * HWD + pix) * (CSPLIT * 10);
    float ab[L1], bsq = 0.f;
    #pragma unroll
    for (int l = 0; l < L1; ++l) ab[l] = 0.f;
    for (int cs = 0; cs < CSPLIT; ++cs) {
        #pragma unroll
        for (int l = 0; l < L1; ++l) ab[l] += pp[cs * 10 + l];
        bsq += pp[cs * 10 + L1];
    }

    float d[L1], mn = 1e30f;
    #pragma unroll
    for (int l = 0; l < L1; ++l) {
        d[l] = bsq - 2.f * ab[l] + asq[l];
        mn = fminf(mn, d[l]);
    }
    float e[L1], sum = 0.f;
    #pragma unroll
    for (int l = 0; l < L1; ++l) {
        e[l] = expf(mn - d[l]);   // exp(-d - max(-d))
        sum += e[l];
    }
    const float inv = 1.f / sum;
    #pragma unroll
    for (int l = 0; l < L1; ++l) {
        size_t o = ((size_t)b * L1 + l) * HWD + pix;
        maps_out[o] = e[l] * inv;
        dist_out[o] = d[l];
    }
}

// ---------------- Kernel C: all_features = feat x maps^T / 784 ----------------
// grid (192, 32): blockIdx.x = c-tile (16 ch), blockIdx.y = b. block 256 = 4 waves.
// Each wave handles 4 channels, lanes over pixels (float4). Writes af (pre-mod)
// to d_out and modulated transpose afT[b][l<8][c] to ws.
__global__ __launch_bounds__(256) void kC(const float* __restrict__ feat,
                                          const float* __restrict__ maps,
                                          const float* __restrict__ modulation,
                                          float* __restrict__ af_out,
                                          float* __restrict__ afT) {
    __shared__ __align__(16) float ms[L1 * HWD];  // 28.2 KB
    const int tid = threadIdx.x;
    const int b = blockIdx.y;
    const float* mb = maps + (size_t)b * L1 * HWD;
    for (int i = tid; i < L1 * HWD; i += 256) ms[i] = mb[i];
    __syncthreads();

    const int wv = tid >> 6, lane = tid & 63;
    const int c0 = blockIdx.x * 16 + wv * 4;
    const float* fb = feat + ((size_t)b * CC + c0) * HWD;

    float acc[4][L1];
    #pragma unroll
    for (int j = 0; j < 4; ++j)
        #pragma unroll
        for (int l = 0; l < L1; ++l) acc[j][l] = 0.f;

    for (int g = lane; g < HWD / 4; g += 64) {
        const int p4 = g * 4;
        float4 m4[L1];
        #pragma unroll
        for (int l = 0; l < L1; ++l) m4[l] = *(const float4*)&ms[l * HWD + p4];
        #pragma unroll
        for (int j = 0; j < 4; ++j) {
            const float4 f = *(const float4*)&fb[(size_t)j * HWD + p4];
            #pragma unroll
            for (int l = 0; l < L1; ++l)
                acc[j][l] += f.x * m4[l].x + f.y * m4[l].y + f.z * m4[l].z + f.w * m4[l].w;
        }
    }
    #pragma unroll
    for (int j = 0; j < 4; ++j)
        #pragma unroll
        for (int l = 0; l < L1; ++l) {
            float v = acc[j][l];
            for (int off = 32; off; off >>= 1) v += __shfl_xor(v, off);
            acc[j][l] = v;
        }
    if (lane == 0) {
        #pragma unroll
        for (int j = 0; j < 4; ++j) {
            const int c = c0 + j;
            #pragma unroll
            for (int l = 0; l < L1; ++l) {
                const float v = acc[j][l] * (1.f / (float)HWD);
                af_out[((size_t)b * CC + c) * L1 + l] = v;
                if (l < 8)
                    afT[((size_t)b * 8 + l) * CC + c] = v * modulation[c * L1 + l];
            }
        }
    }
}

// ---------------- Kernel D: scores = afT x w_cls^T ----------------
// 1600 blocks x 256: wave per (b,k).
__global__ __launch_bounds__(256) void kD(const float* __restrict__ afT,
                                          const float* __restrict__ w_cls,
                                          float* __restrict__ scores) {
    const int wid = blockIdx.x * 4 + (threadIdx.x >> 6);
    const int lane = threadIdx.x & 63;
    const int b = wid / NCLS, k = wid - b * NCLS;
    const float* wk = w_cls + (size_t)k * CC;
    const float* at = afT + (size_t)b * 8 * CC;
    float acc[8];
    #pragma unroll
    for (int l = 0; l < 8; ++l) acc[l] = 0.f;
    for (int c = lane; c < CC; c += 64) {
        const float wv = wk[c];
        #pragma unroll
        for (int l = 0; l < 8; ++l) acc[l] += wv * at[(size_t)l * CC + c];
    }
    #pragma unroll
    for (int l = 0; l < 8; ++l) {
        float v = acc[l];
        for (int off = 32; off; off >>= 1) v += __shfl_xor(v, off);
        acc[l] = v;
    }
    if (lane == 0) {
        #pragma unroll
        for (int l = 0; l < 8; ++l)
            scores[((size_t)b * NCLS + k) * 8 + l] = acc[l];
    }
}

extern "C" void kernel_launch(void* const* d_in, const int* in_sizes, int n_in,
                              void* d_out, int out_size, void* d_ws, size_t ws_size,
                              hipStream_t stream) {
    const float* feat       = (const float*)d_in[0];
    const float* w_land     = (const float*)d_in[1];
    const float* modulation = (const float*)d_in[2];
    const float* w_cls      = (const float*)d_in[3];

    float* out    = (float*)d_out;
    float* af     = out + AF_OFF;
    float* maps   = out + MAPS_OFF;
    float* scores = out + SCORES_OFF;
    float* dist   = out + DIST_OFF;

    float* partial = (float*)d_ws;                       // 32*784*80 = 2,007,040 floats
    float* afT     = partial + (size_t)BB * HWD * 80;    // 32*8*3072 = 786,432 floats

    kA<<<dim3(BB * 4, CSPLIT), 256, 0, stream>>>(feat, w_land, partial);
    kB<<<BB * 4, 256, 0, stream>>>(w_land, partial, maps, dist);
    kC<<<dim3(CC / 16, BB), 256, 0, stream>>>(feat, maps, modulation, af, afT);
    kD<<<BB * NCLS / 4, 256, 0, stream>>>(afT, w_cls, scores);
}

// Round 2
// 519.522 us; speedup vs baseline: 1.1273x; 1.1273x over previous
//
#include <hip/hip_runtime.h>

#define BB 32
#define CC 3072
#define HWD 784     // 28*28
#define L1 9
#define NCLS 200
#define CSPLIT 32
#define CCHUNK 96   // CC / CSPLIT
#define WROW 12     // padded wT row (floats)

// d_out layout (floats):
#define AF_OFF     0
#define MAPS_OFF   884736
#define SCORES_OFF 1110528
#define DIST_OFF   1161728

// ws layout (floats):
#define P_OFF   0
#define P_CNT   (BB*CSPLIT*10*HWD)      // 8,028,160  partial[(b*32+cs)*10+l][pix]
#define WT_OFF  (P_OFF + P_CNT)
#define WT_CNT  (CC*WROW)               // 36,864     wT[c][12] (9 used)
#define ASQ_OFF (WT_OFF + WT_CNT)
#define ASQ_CNT (12*WROW)               // per-block asq partials
#define AFT_OFF (ASQ_OFF + ASQ_CNT)     // afT[b][l][c] modulated, 786,432

// ---------------- kW: transpose w_land -> wT[c][12], per-chunk asq partials ----
__global__ __launch_bounds__(256) void kW(const float* __restrict__ w_land,
                                          float* __restrict__ wT,
                                          float* __restrict__ asqp) {
    __shared__ float red[4][L1];
    const int tid = threadIdx.x;
    const int c = blockIdx.x * 256 + tid;
    float w[L1], s[L1];
    #pragma unroll
    for (int l = 0; l < L1; ++l) w[l] = w_land[l * CC + c];
    #pragma unroll
    for (int l = 0; l < L1; ++l) { wT[c * WROW + l] = w[l]; s[l] = w[l] * w[l]; }
    wT[c * WROW + 9] = 0.f; wT[c * WROW + 10] = 0.f; wT[c * WROW + 11] = 0.f;
    #pragma unroll
    for (int l = 0; l < L1; ++l) {
        float v = s[l];
        for (int off = 32; off; off >>= 1) v += __shfl_xor(v, off);
        s[l] = v;
    }
    const int lane = tid & 63, wv = tid >> 6;
    if (lane == 0) {
        #pragma unroll
        for (int l = 0; l < L1; ++l) red[wv][l] = s[l];
    }
    __syncthreads();
    if (tid == 0) {
        #pragma unroll
        for (int l = 0; l < L1; ++l)
            asqp[blockIdx.x * WROW + l] = red[0][l] + red[1][l] + red[2][l] + red[3][l];
    }
}

// ---------------- kA: partial ab[9]+bsq. grid (32 b, 32 cs), thread = 4 pixels ----
__global__ __launch_bounds__(256) void kA(const float* __restrict__ feat,
                                          const float* __restrict__ wT,
                                          float* __restrict__ partial) {
    const int tid = threadIdx.x;
    if (tid >= HWD / 4) return;          // 196 active threads, no barriers below
    const int b = blockIdx.x, cs = blockIdx.y;
    const int p4 = tid * 4;
    const float* fp = feat + ((size_t)b * CC + (size_t)cs * CCHUNK) * HWD + p4;
    const float* wp = wT + (size_t)cs * CCHUNK * WROW;   // uniform address stream

    float abx[L1], aby[L1], abz[L1], abw[L1];
    #pragma unroll
    for (int l = 0; l < L1; ++l) { abx[l] = 0.f; aby[l] = 0.f; abz[l] = 0.f; abw[l] = 0.f; }
    float bx = 0.f, by = 0.f, bz = 0.f, bw = 0.f;

    #pragma unroll 4
    for (int c = 0; c < CCHUNK; ++c) {
        const float4 f = *(const float4*)&fp[(size_t)c * HWD];
        bx += f.x * f.x; by += f.y * f.y; bz += f.z * f.z; bw += f.w * f.w;
        #pragma unroll
        for (int l = 0; l < L1; ++l) {
            const float w = wp[c * WROW + l];   // wave-uniform -> s_load
            abx[l] += f.x * w; aby[l] += f.y * w; abz[l] += f.z * w; abw[l] += f.w * w;
        }
    }
    float* pout = partial + (size_t)(b * CSPLIT + cs) * 10 * HWD + p4;
    #pragma unroll
    for (int l = 0; l < L1; ++l) {
        float4 o; o.x = abx[l]; o.y = aby[l]; o.z = abz[l]; o.w = abw[l];
        *(float4*)&pout[(size_t)l * HWD] = o;
    }
    float4 o; o.x = bx; o.y = by; o.z = bz; o.w = bw;
    *(float4*)&pout[(size_t)9 * HWD] = o;
}

// ---------------- kB: reduce partials, softmax -> maps, dist ----------------
__global__ __launch_bounds__(256) void kB(const float* __restrict__ partial,
                                          const float* __restrict__ asqp,
                                          float* __restrict__ maps_out,
                                          float* __restrict__ dist_out) {
    const int b = blockIdx.x >> 2, pb = blockIdx.x & 3;
    const int pix = pb * 256 + threadIdx.x;
    if (pix >= HWD) return;

    float asq[L1];
    #pragma unroll
    for (int l = 0; l < L1; ++l) {
        float s = 0.f;
        #pragma unroll
        for (int bc = 0; bc < 12; ++bc) s += asqp[bc * WROW + l];  // uniform
        asq[l] = s;
    }

    float ab[L1], bsq = 0.f;
    #pragma unroll
    for (int l = 0; l < L1; ++l) ab[l] = 0.f;
    const float* pp = partial + (size_t)b * CSPLIT * 10 * HWD + pix;
    #pragma unroll 4
    for (int cs = 0; cs < CSPLIT; ++cs) {
        const float* q = pp + (size_t)cs * 10 * HWD;
        #pragma unroll
        for (int l = 0; l < L1; ++l) ab[l] += q[(size_t)l * HWD];
        bsq += q[(size_t)9 * HWD];
    }

    float d[L1], mn = 1e30f;
    #pragma unroll
    for (int l = 0; l < L1; ++l) {
        d[l] = bsq - 2.f * ab[l] + asq[l];
        mn = fminf(mn, d[l]);
    }
    float e[L1], sum = 0.f;
    #pragma unroll
    for (int l = 0; l < L1; ++l) {
        e[l] = __expf(mn - d[l]);
        sum += e[l];
    }
    const float inv = 1.f / sum;
    #pragma unroll
    for (int l = 0; l < L1; ++l) {
        const size_t o = ((size_t)b * L1 + l) * HWD + pix;
        maps_out[o] = e[l] * inv;
        dist_out[o] = d[l];
    }
}

// ---------------- kC: all_features = feat x maps^T / 784 (no LDS) ----------------
// grid (192, 32): x = 16-channel tile, y = b. 4 waves x 4 channels, lanes over pixel-float4.
__global__ __launch_bounds__(256) void kC(const float* __restrict__ feat,
                                          const float* __restrict__ maps,
                                          const float* __restrict__ modulation,
                                          float* __restrict__ af_out,
                                          float* __restrict__ afT) {
    const int wv = threadIdx.x >> 6, lane = threadIdx.x & 63;
    const int b = blockIdx.y;
    const int c0 = blockIdx.x * 16 + wv * 4;
    const float* fb = feat + ((size_t)b * CC + c0) * HWD;
    const float* mb = maps + (size_t)b * L1 * HWD;

    float acc[4][L1];
    #pragma unroll
    for (int j = 0; j < 4; ++j)
        #pragma unroll
        for (int l = 0; l < L1; ++l) acc[j][l] = 0.f;

    for (int g = lane; g < HWD / 4; g += 64) {
        const int p4 = g * 4;
        float4 m4[L1];
        #pragma unroll
        for (int l = 0; l < L1; ++l) m4[l] = *(const float4*)&mb[(size_t)l * HWD + p4];
        #pragma unroll
        for (int j = 0; j < 4; ++j) {
            const float4 f = *(const float4*)&fb[(size_t)j * HWD + p4];
            #pragma unroll
            for (int l = 0; l < L1; ++l)
                acc[j][l] += f.x * m4[l].x + f.y * m4[l].y + f.z * m4[l].z + f.w * m4[l].w;
        }
    }
    #pragma unroll
    for (int j = 0; j < 4; ++j)
        #pragma unroll
        for (int l = 0; l < L1; ++l) {
            float v = acc[j][l];
            for (int off = 32; off; off >>= 1) v += __shfl_xor(v, off);
            acc[j][l] = v;
        }
    if (lane == 0) {
        #pragma unroll
        for (int j = 0; j < 4; ++j) {
            const int c = c0 + j;
            #pragma unroll
            for (int l = 0; l < L1; ++l) {
                const float v = acc[j][l] * (1.f / (float)HWD);
                af_out[((size_t)b * CC + c) * L1 + l] = v;
                if (l < 8)
                    afT[((size_t)b * 8 + l) * CC + c] = v * modulation[c * L1 + l];
            }
        }
    }
}

// ---------------- kD: scores = afT x w_cls^T. wave per (b, 2 classes) -----------
__global__ __launch_bounds__(256) void kD(const float* __restrict__ afT,
                                          const float* __restrict__ w_cls,
                                          float* __restrict__ scores) {
    const int wid = blockIdx.x * 4 + (threadIdx.x >> 6);
    const int lane = threadIdx.x & 63;
    const int b = wid / (NCLS / 2), kp = wid - b * (NCLS / 2);
    const int k0 = kp * 2;
    const float* at = afT + (size_t)b * 8 * CC;
    const float* w0 = w_cls + (size_t)k0 * CC;
    const float* w1 = w0 + CC;

    float acc[2][8];
    #pragma unroll
    for (int kk = 0; kk < 2; ++kk)
        #pragma unroll
        for (int l = 0; l < 8; ++l) acc[kk][l] = 0.f;

    #pragma unroll 2
    for (int it = 0; it < CC / 256; ++it) {      // 12 iters
        const int c4 = (lane + it * 64) * 4;
        const float4 wa = *(const float4*)&w0[c4];
        const float4 wb = *(const float4*)&w1[c4];
        #pragma unroll
        for (int l = 0; l < 8; ++l) {
            const float4 a = *(const float4*)&at[(size_t)l * CC + c4];
            acc[0][l] += wa.x * a.x + wa.y * a.y + wa.z * a.z + wa.w * a.w;
            acc[1][l] += wb.x * a.x + wb.y * a.y + wb.z * a.z + wb.w * a.w;
        }
    }
    #pragma unroll
    for (int kk = 0; kk < 2; ++kk)
        #pragma unroll
        for (int l = 0; l < 8; ++l) {
            float v = acc[kk][l];
            for (int off = 32; off; off >>= 1) v += __shfl_xor(v, off);
            acc[kk][l] = v;
        }
    if (lane == 0) {
        #pragma unroll
        for (int kk = 0; kk < 2; ++kk)
            #pragma unroll
            for (int l = 0; l < 8; ++l)
                scores[((size_t)b * NCLS + k0 + kk) * 8 + l] = acc[kk][l];
    }
}

extern "C" void kernel_launch(void* const* d_in, const int* in_sizes, int n_in,
                              void* d_out, int out_size, void* d_ws, size_t ws_size,
                              hipStream_t stream) {
    const float* feat       = (const float*)d_in[0];
    const float* w_land     = (const float*)d_in[1];
    const float* modulation = (const float*)d_in[2];
    const float* w_cls      = (const float*)d_in[3];

    float* out    = (float*)d_out;
    float* af     = out + AF_OFF;
    float* maps   = out + MAPS_OFF;
    float* scores = out + SCORES_OFF;
    float* dist   = out + DIST_OFF;

    float* ws      = (float*)d_ws;
    float* partial = ws + P_OFF;
    float* wT      = ws + WT_OFF;
    float* asqp    = ws + ASQ_OFF;
    float* afT     = ws + AFT_OFF;

    kW<<<CC / 256, 256, 0, stream>>>(w_land, wT, asqp);
    kA<<<dim3(BB, CSPLIT), 256, 0, stream>>>(feat, wT, partial);
    kB<<<BB * 4, 256, 0, stream>>>(partial, asqp, maps, dist);
    kC<<<dim3(CC / 16, BB), 256, 0, stream>>>(feat, maps, modulation, af, afT);
    kD<<<BB * NCLS / 2 / 4, 256, 0, stream>>>(afT, w_cls, scores);
}